// Round 7
// baseline (467.327 us; speedup 1.0000x reference)
//
#include <hip/hip_runtime.h>

typedef __attribute__((ext_vector_type(8))) short short8;
typedef __attribute__((ext_vector_type(8))) int int8v;
typedef __attribute__((ext_vector_type(16))) float floatx16;
typedef __attribute__((ext_vector_type(4))) unsigned int uint4v;
typedef unsigned short ushort_t;
typedef unsigned int uint_t;
typedef unsigned char uchar_t;

#define NA   256
#define CIN  128
#define HFD  320
#define FMPX (HFD*HFD)
#define IMGD 1280

// ws layout (bytes):
//   [0, 1MB)              logits f32 (NA*1024)
//   [1MB, +294912)        w1b fp8  [tap][g][nt][c][lane64][32B]  (coalesced B-frag layout), scaled x64
//   [+294912, +311296)    w2r bf16 [32 krow][256 oc]
//   [1.5MB, +1024)        cnt  u32 [256]  per-anchor completion counters
//   [2MB, 2MB+13107200)   fmT fp8  [320 y][320 x][128 c]
#define W1R_BYTE_OFF (1u<<20)
#define W2R_BYTE_OFF ((1u<<20) + 9*256*128)
#define CNT_BYTE_OFF (1536u<<10)
#define FMT_BYTE_OFF (2u<<20)

#define SAPL_Q 5440               // A sub-plane bytes: 340 cells (10 rows x 34 cols) * 16
#define PSTR_Q 4112               // bytes per oc-octet plane of s_h: 8*32*16 + 16 pad

union V32 { int8v v; uint4v q[2]; };

__device__ __forceinline__ ushort_t f2bf(float v) {
    uint_t u = __float_as_uint(v);
    return (ushort_t)((u + 0x8000u) >> 16);
}
__device__ __forceinline__ uchar_t f2fp8(float v) {
    int r = __builtin_amdgcn_cvt_pk_fp8_f32(v, 0.0f, 0, false);
    return (uchar_t)(r & 0xff);
}

// Fused prep: [0,3200) fm->fmT transpose/quantize; [3200,4224) logits zero;
// [4224,4352) w1b repack; 4352: w2r + out + cnt. One launch instead of two.
__global__ __launch_bounds__(256) void prep_kernel(
    const float* __restrict__ W1, const float* __restrict__ W2,
    const float* __restrict__ fm,
    float* __restrict__ logits, float* __restrict__ out,
    uchar_t* __restrict__ w1b, ushort_t* __restrict__ w2r,
    uchar_t* __restrict__ fmT, uint_t* __restrict__ cnt)
{
    const int b = blockIdx.x, t = threadIdx.x;
    __shared__ uchar_t s[32 * 176];   // stride 176 (16-aligned, non-pow2) to spread banks
    if (b < 3200) {
        const int y = b / 10, x0b = (b % 10) * 32;
        #pragma unroll
        for (int i = 0; i < 16; ++i) {
            int e = t + 256 * i;
            int c = e >> 5, xo = e & 31;
            s[xo * 176 + c] = f2fp8(fm[(size_t)c * FMPX + y * HFD + x0b + xo]);
        }
        __syncthreads();
        int xo = t >> 3, cg = t & 7;
        uint4v v = *(const uint4v*)&s[xo * 176 + cg * 16];
        *(uint4v*)&fmT[((size_t)(y * HFD + x0b + xo)) * 128 + cg * 16] = v;
    } else if (b < 4224) {
        logits[(b - 3200) * 256 + t] = 0.0f;
    } else if (b < 4352) {
        int e = (b - 4224) * 256 + t;
        int oc = e >> 7, cin = e & 127;
        int g = oc >> 6, nt = (oc >> 5) & 1, lv = oc & 31;
        int c = cin >> 6, kh = (cin >> 5) & 1, j = cin & 31;
        #pragma unroll
        for (int tap = 0; tap < 9; ++tap) {
            int idx = (((((tap * 4 + g) * 2 + nt) * 2 + c) * 64) + kh * 32 + lv) * 32 + j;
            w1b[idx] = f2fp8(W1[(oc * 128 + cin) * 9 + tap] * 64.0f);
        }
    } else {
        #pragma unroll
        for (int i = 0; i < 32; ++i) {
            int e = i * 256 + t;
            int nrow = e >> 8, oc = e & 255;
            w2r[nrow * 256 + oc] = f2bf(nrow < 9 ? W2[oc * 9 + nrow] : 0.0f);
        }
        cnt[t] = 0u;
        if (t == 0) out[0] = 0.0f;
    }
}

// Block = (anchor, 8-row quarter, 64-oc group); grid 4096, XCD-swizzled.
// Main loop = R6 (FROZEN; best-known): (c rolled, gi=kx rolled, ky unrolled 0..2),
// static 3-buffer B rotation (distance-2 L2 prefetch, no rotate movs), 4 shared A-frags
// per gi off one LDS address. 27% MfmaUtil across R0/R3/R6 structural variants ->
// K-loop is at its structural floor; do not re-tune it without new counter evidence.
// SPILL HISTORY: window-widening spills (R1 450MB / R2 253MB / R4 1.7GB); R5 A-dbuf
// rotate movs -12%. Keep: static names, unconditional loads, rolled gi, (256,3).
// NEW (R7): BCE FUSED into tail -- 16th block per anchor (device-scope cnt atomic,
// threadfence-ordered) computes BCE via __hip_atomic_load(AGENT) on logits (logits
// written by device-scope atomicAdd -> L2-coherent point; cross-XCD safe).
__global__ __launch_bounds__(256, 3) void conv_mfma_kernel(
    const int* __restrict__ anchors, const uchar_t* __restrict__ fmT,
    const uchar_t* __restrict__ w1b, const ushort_t* __restrict__ w2r,
    const float* __restrict__ b1, float* __restrict__ logits,
    const int* __restrict__ seg, const int* __restrict__ labels,
    const int* __restrict__ base_classes, const float* __restrict__ b2,
    float* __restrict__ out, uint_t* __restrict__ cnt)
{
    const int id   = blockIdx.x;
    const int xcd  = id & 7, sid = id >> 3;
    const int n    = xcd * 32 + (sid >> 4);
    const int rem  = sid & 15;
    const int q    = rem >> 2;
    const int g    = rem & 3;

    const int t    = threadIdx.x;
    const int w    = t >> 6;
    const int lane = t & 63;
    const int l31  = lane & 31;
    const int kh   = lane >> 5;

    const int x0 = anchors[n * 4 + 0];
    const int y0 = anchors[n * 4 + 2];
    const int r0 = q * 8;

    __shared__ __align__(16) char smem[8 * PSTR_Q];   // 32896 B: s_a(21760) / s_h / s_log union
    __shared__ int s_done;
    char* s_a = smem;

    // zero col pads (cols 0 & 33 of 10 rows, 4 sub-planes) — persist across both chunks
    if (t < 80) {
        int sub = t & 3, k = t >> 2;
        int pr = k >> 1, col = (k & 1) * 33;
        uint4v z = {0u, 0u, 0u, 0u};
        *(uint4v*)(s_a + sub * SAPL_Q + (pr * 34 + col) * 16) = z;
    }

    floatx16 acc[2][2];
    #pragma unroll
    for (int mt = 0; mt < 2; ++mt)
        #pragma unroll
        for (int nt = 0; nt < 2; ++nt)
            #pragma unroll
            for (int r = 0; r < 16; ++r) acc[mt][nt][r] = 0.0f;

    // B-fragment loader: tap in [0,9), cc = cin chunk
    auto loadB = [&](int tap, int cc, V32* b) {
        #pragma unroll
        for (int nt = 0; nt < 2; ++nt) {
            const uchar_t* bp = w1b + ((((tap * 4 + g) * 2 + nt) * 2 + cc) << 11) + lane * 32;
            b[nt].q[0] = *(const uint4v*)(bp);
            b[nt].q[1] = *(const uint4v*)(bp + 16);
        }
    };

#define MF4(AL, AH, BB)                                                                   \
    acc[0][0] = __builtin_amdgcn_mfma_scale_f32_32x32x64_f8f6f4(                          \
        (AL).v, (BB)[0].v, acc[0][0], 0, 0, 0, 127, 0, 127);                              \
    acc[0][1] = __builtin_amdgcn_mfma_scale_f32_32x32x64_f8f6f4(                          \
        (AL).v, (BB)[1].v, acc[0][1], 0, 0, 0, 127, 0, 127);                              \
    acc[1][0] = __builtin_amdgcn_mfma_scale_f32_32x32x64_f8f6f4(                          \
        (AH).v, (BB)[0].v, acc[1][0], 0, 0, 0, 127, 0, 127);                              \
    acc[1][1] = __builtin_amdgcn_mfma_scale_f32_32x32x64_f8f6f4(                          \
        (AH).v, (BB)[1].v, acc[1][1], 0, 0, 0, 127, 0, 127);

    V32 bb0[2], bb1[2], bb2[2];
    // prime: s=0 -> (kx=0,ky=0) tap 0; s=1 -> (kx=0,ky=1) tap 3; both chunk 0
    loadB(0, 0, bb0);
    loadB(3, 0, bb1);

    #pragma unroll 1
    for (int c = 0; c < 2; ++c) {
        __syncthreads();   // c0: pad zeros visible; c1: all waves done reading chunk0
        // ---- stage A: 10 rows x 32 real cols x 4 subs = 1280 uint4 units (5 iters) ----
        // invalid halo rows (cr outside [0,32)) are written as zeros (conv SAME pad)
        #pragma unroll
        for (int j = 0; j < 5; ++j) {
            int u = t + 256 * j;
            int pr = u >> 7, rr = u & 127;
            int cell = rr >> 2, sub = rr & 3;
            int cr = r0 + pr - 1;
            uint4v v = {0u, 0u, 0u, 0u};
            if ((unsigned)cr < 32u)
                v = *(const uint4v*)&fmT[((size_t)((y0 + cr) * HFD + x0 + cell)) * 128 + c * 64 + sub * 16];
            *(uint4v*)(s_a + sub * SAPL_Q + (pr * 34 + cell + 1) * 16) = v;
        }
        __syncthreads();

        // ---- MFMA: gi = kx rolled; ky unrolled with static buffer naming ----
        #pragma unroll 1
        for (int gi = 0; gi < 3; ++gi) {
            // 4 shared A-frags: rows 2w..2w+3 at col offset gi (one addr + imm offsets)
            V32 fa0, fa1, fa2, fa3;
            {
                const char* ap = s_a + (2 * kh) * SAPL_Q + ((2 * w) * 34 + l31 + gi) * 16;
                fa0.q[0] = *(const uint4v*)(ap);
                fa0.q[1] = *(const uint4v*)(ap + SAPL_Q);
                fa1.q[0] = *(const uint4v*)(ap + 544);
                fa1.q[1] = *(const uint4v*)(ap + SAPL_Q + 544);
                fa2.q[0] = *(const uint4v*)(ap + 1088);
                fa2.q[1] = *(const uint4v*)(ap + SAPL_Q + 1088);
                fa3.q[0] = *(const uint4v*)(ap + 1632);
                fa3.q[1] = *(const uint4v*)(ap + SAPL_Q + 1632);
            }
            // boundary-aware prefetch taps (affine in gi; unconditional loads)
            const int last = (gi == 2);
            const int tapk1 = last ? 0 : gi + 1;      // next step (gi+1,0) / next chunk (0,0)
            const int tapk2 = last ? 3 : gi + 4;      // next step (gi+1,1) / next chunk (0,1)
            const int ccn   = last ? 1 : c;           // c==1,gi==2: dead reload of cc=1 (harmless)

            // k=0: consume bb0; prefetch bb2 for (gi, k=2), tap 6+gi
            loadB(6 + gi, c, bb2);
            MF4(fa0, fa1, bb0)
            // k=1: consume bb1; prefetch bb0 for (gi+1, k=0)
            loadB(tapk1, ccn, bb0);
            MF4(fa1, fa2, bb1)
            // k=2: consume bb2; prefetch bb1 for (gi+1, k=1)
            loadB(tapk2, ccn, bb1);
            MF4(fa2, fa3, bb2)
        }
    }
#undef MF4

    // ---- epilogue: h = acc/64 + b1, relu -> s_h (bf16, 8 planes of 8 oc) ----
    __syncthreads();
    #pragma unroll
    for (int nt = 0; nt < 2; ++nt) {
        float bias = b1[g * 64 + nt * 32 + l31];
        int plane = nt * 4 + (l31 >> 3);
        #pragma unroll
        for (int mt = 0; mt < 2; ++mt) {
            int lr = 2 * w + mt;
            #pragma unroll
            for (int reg = 0; reg < 16; ++reg) {
                int col = (reg & 3) + 8 * (reg >> 2) + 4 * kh;   // C layout: m = crop col
                float hv = fmaxf(fmaf(acc[mt][nt][reg], 0.015625f, bias), 0.0f);
                *(ushort_t*)(smem + plane * PSTR_Q + ((lr * 32 + col) * 8 + (l31 & 7)) * 2) = f2bf(hv);
            }
        }
    }
    __syncthreads();

    // ---- v_tap = h @ W2^T (bf16, K=64 oc over 4 x K16) ----
    floatx16 vacc[2];
    #pragma unroll
    for (int mt = 0; mt < 2; ++mt)
        #pragma unroll
        for (int r = 0; r < 16; ++r) vacc[mt][r] = 0.0f;
    #pragma unroll
    for (int ks = 0; ks < 4; ++ks) {
        short8 bw = *(const short8*)&w2r[l31 * 256 + g * 64 + ks * 16 + kh * 8];
        #pragma unroll
        for (int mt = 0; mt < 2; ++mt) {
            short8 ah = *(const short8*)(smem + (ks * 2 + kh) * PSTR_Q + ((2 * w + mt) * 32 + l31) * 16);
            vacc[mt] = __builtin_amdgcn_mfma_f32_32x32x16_bf16(ah, bw, vacc[mt], 0, 0, 0);
        }
    }

    // ---- scatter v_tap into 10x32 tile (s_h now dead -> union), then global atomics ----
    __syncthreads();
    float* s_log = (float*)smem;
    for (int i = t; i < 320; i += 256) s_log[i] = 0.0f;
    __syncthreads();
    if (l31 < 9) {
        int ky = l31 / 3, kx = l31 - ky * 3;
        #pragma unroll
        for (int mt = 0; mt < 2; ++mt) {
            int outr = 2 * w + mt + 2 - ky;       // tile row; R = r0 + outr - 1
            #pragma unroll
            for (int reg = 0; reg < 16; ++reg) {
                int col  = (reg & 3) + 8 * (reg >> 2) + 4 * kh;
                int outc = col + 1 - kx;
                if (outc >= 0 && outc < 32)
                    atomicAdd(&s_log[outr * 32 + outc], vacc[mt][reg]);
            }
        }
    }
    __syncthreads();
    for (int i = t; i < 320; i += 256) {
        int outr = i >> 5, outc = i & 31;
        int R = r0 + outr - 1;
        if ((unsigned)R < 32u)
            atomicAdd(&logits[n * 1024 + R * 32 + outc], s_log[i]);
    }

    // ---- fused BCE tail: last block of anchor n reduces its 1024 logits ----
    __threadfence();
    __syncthreads();
    if (t == 0) {
        uint_t old = atomicAdd(&cnt[n], 1u);
        s_done = (old == 15u) ? 1 : 0;
    }
    __syncthreads();
    if (s_done) {
        __threadfence();
        const int tgt_cls = base_classes[labels[n]];
        const float bias2 = b2[0];
        float lsum = 0.0f;
        #pragma unroll
        for (int r = 0; r < 4; ++r) {
            int p = t + r * 256;
            int i = p >> 5, j = p & 31;
            float l = __hip_atomic_load(&logits[n * 1024 + p],
                                        __ATOMIC_RELAXED, __HIP_MEMORY_SCOPE_AGENT) + bias2;
            int sv = seg[(size_t)(4 * (y0 + i)) * IMGD + 4 * (x0 + j)];
            float tgt = (sv == tgt_cls) ? 1.0f : 0.0f;
            lsum += fmaxf(l, 0.0f) - l * tgt + log1pf(expf(-fabsf(l)));
        }
        #pragma unroll
        for (int off = 32; off > 0; off >>= 1) lsum += __shfl_down(lsum, off, 64);
        float* s_red = (float*)smem;
        if ((t & 63) == 0) s_red[t >> 6] = lsum;
        __syncthreads();
        if (t == 0) {
            float tot = s_red[0] + s_red[1] + s_red[2] + s_red[3];
            const float scale = 1.0f / (1024.0f * (256.0f + 1e-10f));
            atomicAdd(out, tot * scale);
        }
    }
}

extern "C" void kernel_launch(void* const* d_in, const int* in_sizes, int n_in,
                              void* d_out, int out_size, void* d_ws, size_t ws_size,
                              hipStream_t stream) {
    const float* fm           = (const float*)d_in[0];
    const int*   seg          = (const int*)d_in[1];
    const int*   anchors      = (const int*)d_in[2];
    const int*   labels       = (const int*)d_in[3];
    const int*   base_classes = (const int*)d_in[4];
    const float* W1           = (const float*)d_in[5];
    const float* b1           = (const float*)d_in[6];
    const float* W2           = (const float*)d_in[7];
    const float* b2           = (const float*)d_in[8];
    float* out = (float*)d_out;

    float*    logits = (float*)d_ws;
    uchar_t*  w1b    = (uchar_t*)((char*)d_ws + W1R_BYTE_OFF);
    ushort_t* w2r    = (ushort_t*)((char*)d_ws + W2R_BYTE_OFF);
    uint_t*   cnt    = (uint_t*)((char*)d_ws + CNT_BYTE_OFF);
    uchar_t*  fmT    = (uchar_t*)((char*)d_ws + FMT_BYTE_OFF);

    prep_kernel<<<4353, 256, 0, stream>>>(W1, W2, fm, logits, out, w1b, w2r, fmT, cnt);
    conv_mfma_kernel<<<4096, 256, 0, stream>>>(anchors, fmT, w1b, w2r, b1, logits,
                                               seg, labels, base_classes, b2, out, cnt);
}

// Round 9
// 226.190 us; speedup vs baseline: 2.0661x; 2.0661x over previous
//
#include <hip/hip_runtime.h>

typedef __attribute__((ext_vector_type(8))) short short8;
typedef __attribute__((ext_vector_type(8))) int int8v;
typedef __attribute__((ext_vector_type(16))) float floatx16;
typedef __attribute__((ext_vector_type(4))) unsigned int uint4v;
typedef unsigned short ushort_t;
typedef unsigned int uint_t;
typedef unsigned char uchar_t;

#define NA   256
#define CIN  128
#define HFD  320
#define FMPX (HFD*HFD)
#define IMGD 1280

// ws layout (bytes):
//   [0, 1MB)              logits f32 (NA*1024)
//   [1MB, +294912)        w1b fp8  [tap][g][nt][c][lane64][32B]  (coalesced B-frag layout), scaled x64
//   [+294912, +311296)    w2r bf16 [32 krow][256 oc]
//   [1.5MB, +1024)        cnt  u32 [256]  per-anchor completion counters
//   [2MB, 2MB+13107200)   fmT fp8  [320 y][320 x][128 c]
#define W1R_BYTE_OFF (1u<<20)
#define W2R_BYTE_OFF ((1u<<20) + 9*256*128)
#define CNT_BYTE_OFF (1536u<<10)
#define FMT_BYTE_OFF (2u<<20)

#define SAPL_Q 5440               // A sub-plane bytes: 340 cells (10 rows x 34 cols) * 16
#define PSTR_Q 4112               // bytes per oc-octet plane of s_h: 8*32*16 + 16 pad

union V32 { int8v v; uint4v q[2]; };

__device__ __forceinline__ ushort_t f2bf(float v) {
    uint_t u = __float_as_uint(v);
    return (ushort_t)((u + 0x8000u) >> 16);
}
__device__ __forceinline__ uchar_t f2fp8(float v) {
    int r = __builtin_amdgcn_cvt_pk_fp8_f32(v, 0.0f, 0, false);
    return (uchar_t)(r & 0xff);
}

// Fused prep: [0,3200) fm->fmT transpose/quantize; [3200,4224) logits zero;
// [4224,4352) w1b repack; 4352: w2r + out + cnt. One launch instead of two.
__global__ __launch_bounds__(256) void prep_kernel(
    const float* __restrict__ W1, const float* __restrict__ W2,
    const float* __restrict__ fm,
    float* __restrict__ logits, float* __restrict__ out,
    uchar_t* __restrict__ w1b, ushort_t* __restrict__ w2r,
    uchar_t* __restrict__ fmT, uint_t* __restrict__ cnt)
{
    const int b = blockIdx.x, t = threadIdx.x;
    __shared__ uchar_t s[32 * 176];   // stride 176 (16-aligned, non-pow2) to spread banks
    if (b < 3200) {
        const int y = b / 10, x0b = (b % 10) * 32;
        #pragma unroll
        for (int i = 0; i < 16; ++i) {
            int e = t + 256 * i;
            int c = e >> 5, xo = e & 31;
            s[xo * 176 + c] = f2fp8(fm[(size_t)c * FMPX + y * HFD + x0b + xo]);
        }
        __syncthreads();
        int xo = t >> 3, cg = t & 7;
        uint4v v = *(const uint4v*)&s[xo * 176 + cg * 16];
        *(uint4v*)&fmT[((size_t)(y * HFD + x0b + xo)) * 128 + cg * 16] = v;
    } else if (b < 4224) {
        logits[(b - 3200) * 256 + t] = 0.0f;
    } else if (b < 4352) {
        int e = (b - 4224) * 256 + t;
        int oc = e >> 7, cin = e & 127;
        int g = oc >> 6, nt = (oc >> 5) & 1, lv = oc & 31;
        int c = cin >> 6, kh = (cin >> 5) & 1, j = cin & 31;
        #pragma unroll
        for (int tap = 0; tap < 9; ++tap) {
            int idx = (((((tap * 4 + g) * 2 + nt) * 2 + c) * 64) + kh * 32 + lv) * 32 + j;
            w1b[idx] = f2fp8(W1[(oc * 128 + cin) * 9 + tap] * 64.0f);
        }
    } else {
        #pragma unroll
        for (int i = 0; i < 32; ++i) {
            int e = i * 256 + t;
            int nrow = e >> 8, oc = e & 255;
            w2r[nrow * 256 + oc] = f2bf(nrow < 9 ? W2[oc * 9 + nrow] : 0.0f);
        }
        cnt[t] = 0u;
        if (t == 0) out[0] = 0.0f;
    }
}

// Block = (anchor, 8-row quarter, 64-oc group); grid 4096, XCD-swizzled.
// Main loop = R6 (FROZEN; best-known). 27% MfmaUtil across R0/R3/R6 structural
// variants -> K-loop at its structural floor; don't re-tune without new evidence.
// SPILL HISTORY: window-widening spills (R1 450MB / R2 253MB / R4 1.7GB); R5 A-dbuf
// rotate movs -12%. Keep: static names, unconditional loads, rolled gi, (256,3).
// BCE tail (R8): NO __threadfence -- R7's all-blocks agent fence forced per-block L2
// writeback/invalidate, evicting the hot w1b L2 stream chip-wide (conv 122->380 us,
// MfmaUtil 27.7->8.6 with UNCHANGED FETCH/WRITE). Release ordering instead comes from
// the compiler's vmcnt(0) drain at __syncthreads (m97 asm): device-scope logits
// atomics COMPLETED => globally visible (m20: atomicAdd is device-scope, executes at
// the cross-XCD-coherent point). Reader uses __hip_atomic_load(AGENT) (R7-proven).
__global__ __launch_bounds__(256, 3) void conv_mfma_kernel(
    const int* __restrict__ anchors, const uchar_t* __restrict__ fmT,
    const uchar_t* __restrict__ w1b, const ushort_t* __restrict__ w2r,
    const float* __restrict__ b1, float* __restrict__ logits,
    const int* __restrict__ seg, const int* __restrict__ labels,
    const int* __restrict__ base_classes, const float* __restrict__ b2,
    float* __restrict__ out, uint_t* __restrict__ cnt)
{
    const int id   = blockIdx.x;
    const int xcd  = id & 7, sid = id >> 3;
    const int n    = xcd * 32 + (sid >> 4);
    const int rem  = sid & 15;
    const int q    = rem >> 2;
    const int g    = rem & 3;

    const int t    = threadIdx.x;
    const int w    = t >> 6;
    const int lane = t & 63;
    const int l31  = lane & 31;
    const int kh   = lane >> 5;

    const int x0 = anchors[n * 4 + 0];
    const int y0 = anchors[n * 4 + 2];
    const int r0 = q * 8;

    __shared__ __align__(16) char smem[8 * PSTR_Q];   // 32896 B: s_a(21760) / s_h / s_log union
    __shared__ int s_done;
    char* s_a = smem;

    // zero col pads (cols 0 & 33 of 10 rows, 4 sub-planes) — persist across both chunks
    if (t < 80) {
        int sub = t & 3, k = t >> 2;
        int pr = k >> 1, col = (k & 1) * 33;
        uint4v z = {0u, 0u, 0u, 0u};
        *(uint4v*)(s_a + sub * SAPL_Q + (pr * 34 + col) * 16) = z;
    }

    floatx16 acc[2][2];
    #pragma unroll
    for (int mt = 0; mt < 2; ++mt)
        #pragma unroll
        for (int nt = 0; nt < 2; ++nt)
            #pragma unroll
            for (int r = 0; r < 16; ++r) acc[mt][nt][r] = 0.0f;

    // B-fragment loader: tap in [0,9), cc = cin chunk
    auto loadB = [&](int tap, int cc, V32* b) {
        #pragma unroll
        for (int nt = 0; nt < 2; ++nt) {
            const uchar_t* bp = w1b + ((((tap * 4 + g) * 2 + nt) * 2 + cc) << 11) + lane * 32;
            b[nt].q[0] = *(const uint4v*)(bp);
            b[nt].q[1] = *(const uint4v*)(bp + 16);
        }
    };

#define MF4(AL, AH, BB)                                                                   \
    acc[0][0] = __builtin_amdgcn_mfma_scale_f32_32x32x64_f8f6f4(                          \
        (AL).v, (BB)[0].v, acc[0][0], 0, 0, 0, 127, 0, 127);                              \
    acc[0][1] = __builtin_amdgcn_mfma_scale_f32_32x32x64_f8f6f4(                          \
        (AL).v, (BB)[1].v, acc[0][1], 0, 0, 0, 127, 0, 127);                              \
    acc[1][0] = __builtin_amdgcn_mfma_scale_f32_32x32x64_f8f6f4(                          \
        (AH).v, (BB)[0].v, acc[1][0], 0, 0, 0, 127, 0, 127);                              \
    acc[1][1] = __builtin_amdgcn_mfma_scale_f32_32x32x64_f8f6f4(                          \
        (AH).v, (BB)[1].v, acc[1][1], 0, 0, 0, 127, 0, 127);

    V32 bb0[2], bb1[2], bb2[2];
    // prime: s=0 -> (kx=0,ky=0) tap 0; s=1 -> (kx=0,ky=1) tap 3; both chunk 0
    loadB(0, 0, bb0);
    loadB(3, 0, bb1);

    #pragma unroll 1
    for (int c = 0; c < 2; ++c) {
        __syncthreads();   // c0: pad zeros visible; c1: all waves done reading chunk0
        // ---- stage A: 10 rows x 32 real cols x 4 subs = 1280 uint4 units (5 iters) ----
        // invalid halo rows (cr outside [0,32)) are written as zeros (conv SAME pad)
        #pragma unroll
        for (int j = 0; j < 5; ++j) {
            int u = t + 256 * j;
            int pr = u >> 7, rr = u & 127;
            int cell = rr >> 2, sub = rr & 3;
            int cr = r0 + pr - 1;
            uint4v v = {0u, 0u, 0u, 0u};
            if ((unsigned)cr < 32u)
                v = *(const uint4v*)&fmT[((size_t)((y0 + cr) * HFD + x0 + cell)) * 128 + c * 64 + sub * 16];
            *(uint4v*)(s_a + sub * SAPL_Q + (pr * 34 + cell + 1) * 16) = v;
        }
        __syncthreads();

        // ---- MFMA: gi = kx rolled; ky unrolled with static buffer naming ----
        #pragma unroll 1
        for (int gi = 0; gi < 3; ++gi) {
            // 4 shared A-frags: rows 2w..2w+3 at col offset gi (one addr + imm offsets)
            V32 fa0, fa1, fa2, fa3;
            {
                const char* ap = s_a + (2 * kh) * SAPL_Q + ((2 * w) * 34 + l31 + gi) * 16;
                fa0.q[0] = *(const uint4v*)(ap);
                fa0.q[1] = *(const uint4v*)(ap + SAPL_Q);
                fa1.q[0] = *(const uint4v*)(ap + 544);
                fa1.q[1] = *(const uint4v*)(ap + SAPL_Q + 544);
                fa2.q[0] = *(const uint4v*)(ap + 1088);
                fa2.q[1] = *(const uint4v*)(ap + SAPL_Q + 1088);
                fa3.q[0] = *(const uint4v*)(ap + 1632);
                fa3.q[1] = *(const uint4v*)(ap + SAPL_Q + 1632);
            }
            // boundary-aware prefetch taps (affine in gi; unconditional loads)
            const int last = (gi == 2);
            const int tapk1 = last ? 0 : gi + 1;      // next step (gi+1,0) / next chunk (0,0)
            const int tapk2 = last ? 3 : gi + 4;      // next step (gi+1,1) / next chunk (0,1)
            const int ccn   = last ? 1 : c;           // c==1,gi==2: dead reload of cc=1 (harmless)

            // k=0: consume bb0; prefetch bb2 for (gi, k=2), tap 6+gi
            loadB(6 + gi, c, bb2);
            MF4(fa0, fa1, bb0)
            // k=1: consume bb1; prefetch bb0 for (gi+1, k=0)
            loadB(tapk1, ccn, bb0);
            MF4(fa1, fa2, bb1)
            // k=2: consume bb2; prefetch bb1 for (gi+1, k=1)
            loadB(tapk2, ccn, bb1);
            MF4(fa2, fa3, bb2)
        }
    }
#undef MF4

    // ---- epilogue: h = acc/64 + b1, relu -> s_h (bf16, 8 planes of 8 oc) ----
    __syncthreads();
    #pragma unroll
    for (int nt = 0; nt < 2; ++nt) {
        float bias = b1[g * 64 + nt * 32 + l31];
        int plane = nt * 4 + (l31 >> 3);
        #pragma unroll
        for (int mt = 0; mt < 2; ++mt) {
            int lr = 2 * w + mt;
            #pragma unroll
            for (int reg = 0; reg < 16; ++reg) {
                int col = (reg & 3) + 8 * (reg >> 2) + 4 * kh;   // C layout: m = crop col
                float hv = fmaxf(fmaf(acc[mt][nt][reg], 0.015625f, bias), 0.0f);
                *(ushort_t*)(smem + plane * PSTR_Q + ((lr * 32 + col) * 8 + (l31 & 7)) * 2) = f2bf(hv);
            }
        }
    }
    __syncthreads();

    // ---- v_tap = h @ W2^T (bf16, K=64 oc over 4 x K16) ----
    floatx16 vacc[2];
    #pragma unroll
    for (int mt = 0; mt < 2; ++mt)
        #pragma unroll
        for (int r = 0; r < 16; ++r) vacc[mt][r] = 0.0f;
    #pragma unroll
    for (int ks = 0; ks < 4; ++ks) {
        short8 bw = *(const short8*)&w2r[l31 * 256 + g * 64 + ks * 16 + kh * 8];
        #pragma unroll
        for (int mt = 0; mt < 2; ++mt) {
            short8 ah = *(const short8*)(smem + (ks * 2 + kh) * PSTR_Q + ((2 * w + mt) * 32 + l31) * 16);
            vacc[mt] = __builtin_amdgcn_mfma_f32_32x32x16_bf16(ah, bw, vacc[mt], 0, 0, 0);
        }
    }

    // ---- scatter v_tap into 10x32 tile (s_h now dead -> union), then global atomics ----
    __syncthreads();
    float* s_log = (float*)smem;
    for (int i = t; i < 320; i += 256) s_log[i] = 0.0f;
    __syncthreads();
    if (l31 < 9) {
        int ky = l31 / 3, kx = l31 - ky * 3;
        #pragma unroll
        for (int mt = 0; mt < 2; ++mt) {
            int outr = 2 * w + mt + 2 - ky;       // tile row; R = r0 + outr - 1
            #pragma unroll
            for (int reg = 0; reg < 16; ++reg) {
                int col  = (reg & 3) + 8 * (reg >> 2) + 4 * kh;
                int outc = col + 1 - kx;
                if (outc >= 0 && outc < 32)
                    atomicAdd(&s_log[outr * 32 + outc], vacc[mt][reg]);
            }
        }
    }
    __syncthreads();
    for (int i = t; i < 320; i += 256) {
        int outr = i >> 5, outc = i & 31;
        int R = r0 + outr - 1;
        if ((unsigned)R < 32u)
            atomicAdd(&logits[n * 1024 + R * 32 + outc], s_log[i]);
    }

    // ---- fused BCE tail: last block of anchor n reduces its 1024 logits ----
    // NOTE: no __threadfence here (R7 lesson). __syncthreads' compiler-emitted
    // vmcnt(0) drain completes every thread's device-scope logits atomics; completed
    // device-scope atomics are globally visible (m20). Reader loads are AGENT-scope.
    __syncthreads();
    if (t == 0) {
        uint_t old = atomicAdd(&cnt[n], 1u);
        s_done = (old == 15u) ? 1 : 0;
    }
    __syncthreads();
    if (s_done) {
        const int tgt_cls = base_classes[labels[n]];
        const float bias2 = b2[0];
        float lsum = 0.0f;
        #pragma unroll
        for (int r = 0; r < 4; ++r) {
            int p = t + r * 256;
            int i = p >> 5, j = p & 31;
            float l = __hip_atomic_load(&logits[n * 1024 + p],
                                        __ATOMIC_RELAXED, __HIP_MEMORY_SCOPE_AGENT) + bias2;
            int sv = seg[(size_t)(4 * (y0 + i)) * IMGD + 4 * (x0 + j)];
            float tgt = (sv == tgt_cls) ? 1.0f : 0.0f;
            lsum += fmaxf(l, 0.0f) - l * tgt + log1pf(expf(-fabsf(l)));
        }
        #pragma unroll
        for (int off = 32; off > 0; off >>= 1) lsum += __shfl_down(lsum, off, 64);
        float* s_red = (float*)smem;
        if ((t & 63) == 0) s_red[t >> 6] = lsum;
        __syncthreads();
        if (t == 0) {
            float tot = s_red[0] + s_red[1] + s_red[2] + s_red[3];
            const float scale = 1.0f / (1024.0f * (256.0f + 1e-10f));
            atomicAdd(out, tot * scale);
        }
    }
}

extern "C" void kernel_launch(void* const* d_in, const int* in_sizes, int n_in,
                              void* d_out, int out_size, void* d_ws, size_t ws_size,
                              hipStream_t stream) {
    const float* fm           = (const float*)d_in[0];
    const int*   seg          = (const int*)d_in[1];
    const int*   anchors      = (const int*)d_in[2];
    const int*   labels       = (const int*)d_in[3];
    const int*   base_classes = (const int*)d_in[4];
    const float* W1           = (const float*)d_in[5];
    const float* b1           = (const float*)d_in[6];
    const float* W2           = (const float*)d_in[7];
    const float* b2           = (const float*)d_in[8];
    float* out = (float*)d_out;

    float*    logits = (float*)d_ws;
    uchar_t*  w1b    = (uchar_t*)((char*)d_ws + W1R_BYTE_OFF);
    ushort_t* w2r    = (ushort_t*)((char*)d_ws + W2R_BYTE_OFF);
    uint_t*   cnt    = (uint_t*)((char*)d_ws + CNT_BYTE_OFF);
    uchar_t*  fmT    = (uchar_t*)((char*)d_ws + FMT_BYTE_OFF);

    prep_kernel<<<4353, 256, 0, stream>>>(W1, W2, fm, logits, out, w1b, w2r, fmT, cnt);
    conv_mfma_kernel<<<4096, 256, 0, stream>>>(anchors, fmT, w1b, w2r, b1, logits,
                                               seg, labels, base_classes, b2, out, cnt);
}

// Round 10
// 223.884 us; speedup vs baseline: 2.0874x; 1.0103x over previous
//
#include <hip/hip_runtime.h>

typedef __attribute__((ext_vector_type(8))) short short8;
typedef __attribute__((ext_vector_type(8))) int int8v;
typedef __attribute__((ext_vector_type(16))) float floatx16;
typedef __attribute__((ext_vector_type(4))) unsigned int uint4v;
typedef unsigned short ushort_t;
typedef unsigned int uint_t;
typedef unsigned char uchar_t;

#define NA   256
#define CIN  128
#define HFD  320
#define FMPX (HFD*HFD)
#define IMGD 1280

// ws layout (bytes):
//   [0, 1MB)              logits f32 (NA*1024)
//   [1MB, +294912)        w1b fp8  [tap][g][nt][c][lane64][32B]  (coalesced B-frag layout), scaled x64
//   [+294912, +311296)    w2r bf16 [32 krow][256 oc]
//   [1.5MB, +1024)        cnt  u32 [256]  per-anchor completion counters
//   [2MB, 2MB+13107200)   fmT fp8  [320 y][320 x][128 c]
#define W1R_BYTE_OFF (1u<<20)
#define W2R_BYTE_OFF ((1u<<20) + 9*256*128)
#define CNT_BYTE_OFF (1536u<<10)
#define FMT_BYTE_OFF (2u<<20)

#define SAPL_Q 5440               // A sub-plane bytes: 340 cells (10 rows x 34 cols) * 16
#define PSTR_Q 4112               // bytes per oc-octet plane of s_h: 8*32*16 + 16 pad

union V32 { int8v v; uint4v q[2]; };

__device__ __forceinline__ ushort_t f2bf(float v) {
    uint_t u = __float_as_uint(v);
    return (ushort_t)((u + 0x8000u) >> 16);
}
__device__ __forceinline__ uchar_t f2fp8(float v) {
    int r = __builtin_amdgcn_cvt_pk_fp8_f32(v, 0.0f, 0, false);
    return (uchar_t)(r & 0xff);
}

// Fused prep: [0,3200) fm->fmT transpose/quantize; [3200,4224) logits zero;
// [4224,4352) w1b repack; 4352: w2r + out + cnt.
// R10: transpose branch rewritten LDS-FREE. R9 accounting showed prep ~= 85-90 us
// (rest-minus-gaps) vs a 10.5 us BW roofline (52.4 MB read + 13.1 MB write): the old
// path serialized on 13.1M byte-granularity LDS writes (4-way conflicts) + 13.1M
// scalar cvts + barrier. New path: thread (xo=t&31, cg=t>>5) does 16 COALESCED f32
// loads (per k: 32 lanes = 128B contiguous), 8x cvt_pk_fp8_f32 (2 elem/inst), one
// uint4 store. Bit-identical fmT (same cvt instruction per element, same byte order:
// dword d byte j = channel cg*16+4d+j).
__global__ __launch_bounds__(256) void prep_kernel(
    const float* __restrict__ W1, const float* __restrict__ W2,
    const float* __restrict__ fm,
    float* __restrict__ logits, float* __restrict__ out,
    uchar_t* __restrict__ w1b, ushort_t* __restrict__ w2r,
    uchar_t* __restrict__ fmT, uint_t* __restrict__ cnt)
{
    const int b = blockIdx.x, t = threadIdx.x;
    if (b < 3200) {
        const int y = b / 10, x0b = (b % 10) * 32;
        const int xo = t & 31, cg = t >> 5;
        const float* src = fm + (size_t)(cg * 16) * FMPX + (size_t)y * HFD + x0b + xo;
        float f[16];
        #pragma unroll
        for (int k = 0; k < 16; ++k) f[k] = src[(size_t)k * FMPX];
        uint4v vout;
        #pragma unroll
        for (int d = 0; d < 4; ++d) {
            int u = __builtin_amdgcn_cvt_pk_fp8_f32(f[4*d],   f[4*d+1], 0, false);
            u     = __builtin_amdgcn_cvt_pk_fp8_f32(f[4*d+2], f[4*d+3], u, true);
            vout[d] = (uint_t)u;
        }
        *(uint4v*)&fmT[((size_t)(y * HFD + x0b + xo)) * 128 + cg * 16] = vout;
    } else if (b < 4224) {
        logits[(b - 3200) * 256 + t] = 0.0f;
    } else if (b < 4352) {
        int e = (b - 4224) * 256 + t;
        int oc = e >> 7, cin = e & 127;
        int g = oc >> 6, nt = (oc >> 5) & 1, lv = oc & 31;
        int c = cin >> 6, kh = (cin >> 5) & 1, j = cin & 31;
        #pragma unroll
        for (int tap = 0; tap < 9; ++tap) {
            int idx = (((((tap * 4 + g) * 2 + nt) * 2 + c) * 64) + kh * 32 + lv) * 32 + j;
            w1b[idx] = f2fp8(W1[(oc * 128 + cin) * 9 + tap] * 64.0f);
        }
    } else {
        #pragma unroll
        for (int i = 0; i < 32; ++i) {
            int e = i * 256 + t;
            int nrow = e >> 8, oc = e & 255;
            w2r[nrow * 256 + oc] = f2bf(nrow < 9 ? W2[oc * 9 + nrow] : 0.0f);
        }
        cnt[t] = 0u;
        if (t == 0) out[0] = 0.0f;
    }
}

// Block = (anchor, 8-row quarter, 64-oc group); grid 4096, XCD-swizzled.
// Main loop = R6 (FROZEN; best-known). 27% MfmaUtil across R0/R3/R6 structural
// variants -> K-loop at its structural floor; don't re-tune without new evidence.
// SPILL HISTORY: window-widening spills (R1 450MB / R2 253MB / R4 1.7GB); R5 A-dbuf
// rotate movs -12%. Keep: static names, unconditional loads, rolled gi, (256,3).
// BCE tail: NO __threadfence (R7: all-blocks agent fence = per-block L2 writeback,
// evicted hot w1b L2 stream chip-wide, conv 122->380us @ unchanged FETCH/WRITE; R9
// fence-free: conv 131us, absmax 0 -- visibility via vmcnt-drained device-scope
// atomics (m20/m97) + AGENT-scope reader loads. PROVEN. Do not re-add fences.)
__global__ __launch_bounds__(256, 3) void conv_mfma_kernel(
    const int* __restrict__ anchors, const uchar_t* __restrict__ fmT,
    const uchar_t* __restrict__ w1b, const ushort_t* __restrict__ w2r,
    const float* __restrict__ b1, float* __restrict__ logits,
    const int* __restrict__ seg, const int* __restrict__ labels,
    const int* __restrict__ base_classes, const float* __restrict__ b2,
    float* __restrict__ out, uint_t* __restrict__ cnt)
{
    const int id   = blockIdx.x;
    const int xcd  = id & 7, sid = id >> 3;
    const int n    = xcd * 32 + (sid >> 4);
    const int rem  = sid & 15;
    const int q    = rem >> 2;
    const int g    = rem & 3;

    const int t    = threadIdx.x;
    const int w    = t >> 6;
    const int lane = t & 63;
    const int l31  = lane & 31;
    const int kh   = lane >> 5;

    const int x0 = anchors[n * 4 + 0];
    const int y0 = anchors[n * 4 + 2];
    const int r0 = q * 8;

    __shared__ __align__(16) char smem[8 * PSTR_Q];   // 32896 B: s_a(21760) / s_h / s_log union
    __shared__ int s_done;
    char* s_a = smem;

    // zero col pads (cols 0 & 33 of 10 rows, 4 sub-planes) — persist across both chunks
    if (t < 80) {
        int sub = t & 3, k = t >> 2;
        int pr = k >> 1, col = (k & 1) * 33;
        uint4v z = {0u, 0u, 0u, 0u};
        *(uint4v*)(s_a + sub * SAPL_Q + (pr * 34 + col) * 16) = z;
    }

    floatx16 acc[2][2];
    #pragma unroll
    for (int mt = 0; mt < 2; ++mt)
        #pragma unroll
        for (int nt = 0; nt < 2; ++nt)
            #pragma unroll
            for (int r = 0; r < 16; ++r) acc[mt][nt][r] = 0.0f;

    // B-fragment loader: tap in [0,9), cc = cin chunk
    auto loadB = [&](int tap, int cc, V32* b) {
        #pragma unroll
        for (int nt = 0; nt < 2; ++nt) {
            const uchar_t* bp = w1b + ((((tap * 4 + g) * 2 + nt) * 2 + cc) << 11) + lane * 32;
            b[nt].q[0] = *(const uint4v*)(bp);
            b[nt].q[1] = *(const uint4v*)(bp + 16);
        }
    };

#define MF4(AL, AH, BB)                                                                   \
    acc[0][0] = __builtin_amdgcn_mfma_scale_f32_32x32x64_f8f6f4(                          \
        (AL).v, (BB)[0].v, acc[0][0], 0, 0, 0, 127, 0, 127);                              \
    acc[0][1] = __builtin_amdgcn_mfma_scale_f32_32x32x64_f8f6f4(                          \
        (AL).v, (BB)[1].v, acc[0][1], 0, 0, 0, 127, 0, 127);                              \
    acc[1][0] = __builtin_amdgcn_mfma_scale_f32_32x32x64_f8f6f4(                          \
        (AH).v, (BB)[0].v, acc[1][0], 0, 0, 0, 127, 0, 127);                              \
    acc[1][1] = __builtin_amdgcn_mfma_scale_f32_32x32x64_f8f6f4(                          \
        (AH).v, (BB)[1].v, acc[1][1], 0, 0, 0, 127, 0, 127);

    V32 bb0[2], bb1[2], bb2[2];
    // prime: s=0 -> (kx=0,ky=0) tap 0; s=1 -> (kx=0,ky=1) tap 3; both chunk 0
    loadB(0, 0, bb0);
    loadB(3, 0, bb1);

    #pragma unroll 1
    for (int c = 0; c < 2; ++c) {
        __syncthreads();   // c0: pad zeros visible; c1: all waves done reading chunk0
        // ---- stage A: 10 rows x 32 real cols x 4 subs = 1280 uint4 units (5 iters) ----
        // invalid halo rows (cr outside [0,32)) are written as zeros (conv SAME pad)
        #pragma unroll
        for (int j = 0; j < 5; ++j) {
            int u = t + 256 * j;
            int pr = u >> 7, rr = u & 127;
            int cell = rr >> 2, sub = rr & 3;
            int cr = r0 + pr - 1;
            uint4v v = {0u, 0u, 0u, 0u};
            if ((unsigned)cr < 32u)
                v = *(const uint4v*)&fmT[((size_t)((y0 + cr) * HFD + x0 + cell)) * 128 + c * 64 + sub * 16];
            *(uint4v*)(s_a + sub * SAPL_Q + (pr * 34 + cell + 1) * 16) = v;
        }
        __syncthreads();

        // ---- MFMA: gi = kx rolled; ky unrolled with static buffer naming ----
        #pragma unroll 1
        for (int gi = 0; gi < 3; ++gi) {
            // 4 shared A-frags: rows 2w..2w+3 at col offset gi (one addr + imm offsets)
            V32 fa0, fa1, fa2, fa3;
            {
                const char* ap = s_a + (2 * kh) * SAPL_Q + ((2 * w) * 34 + l31 + gi) * 16;
                fa0.q[0] = *(const uint4v*)(ap);
                fa0.q[1] = *(const uint4v*)(ap + SAPL_Q);
                fa1.q[0] = *(const uint4v*)(ap + 544);
                fa1.q[1] = *(const uint4v*)(ap + SAPL_Q + 544);
                fa2.q[0] = *(const uint4v*)(ap + 1088);
                fa2.q[1] = *(const uint4v*)(ap + SAPL_Q + 1088);
                fa3.q[0] = *(const uint4v*)(ap + 1632);
                fa3.q[1] = *(const uint4v*)(ap + SAPL_Q + 1632);
            }
            // boundary-aware prefetch taps (affine in gi; unconditional loads)
            const int last = (gi == 2);
            const int tapk1 = last ? 0 : gi + 1;      // next step (gi+1,0) / next chunk (0,0)
            const int tapk2 = last ? 3 : gi + 4;      // next step (gi+1,1) / next chunk (0,1)
            const int ccn   = last ? 1 : c;           // c==1,gi==2: dead reload of cc=1 (harmless)

            // k=0: consume bb0; prefetch bb2 for (gi, k=2), tap 6+gi
            loadB(6 + gi, c, bb2);
            MF4(fa0, fa1, bb0)
            // k=1: consume bb1; prefetch bb0 for (gi+1, k=0)
            loadB(tapk1, ccn, bb0);
            MF4(fa1, fa2, bb1)
            // k=2: consume bb2; prefetch bb1 for (gi+1, k=1)
            loadB(tapk2, ccn, bb1);
            MF4(fa2, fa3, bb2)
        }
    }
#undef MF4

    // ---- epilogue: h = acc/64 + b1, relu -> s_h (bf16, 8 planes of 8 oc) ----
    __syncthreads();
    #pragma unroll
    for (int nt = 0; nt < 2; ++nt) {
        float bias = b1[g * 64 + nt * 32 + l31];
        int plane = nt * 4 + (l31 >> 3);
        #pragma unroll
        for (int mt = 0; mt < 2; ++mt) {
            int lr = 2 * w + mt;
            #pragma unroll
            for (int reg = 0; reg < 16; ++reg) {
                int col = (reg & 3) + 8 * (reg >> 2) + 4 * kh;   // C layout: m = crop col
                float hv = fmaxf(fmaf(acc[mt][nt][reg], 0.015625f, bias), 0.0f);
                *(ushort_t*)(smem + plane * PSTR_Q + ((lr * 32 + col) * 8 + (l31 & 7)) * 2) = f2bf(hv);
            }
        }
    }
    __syncthreads();

    // ---- v_tap = h @ W2^T (bf16, K=64 oc over 4 x K16) ----
    floatx16 vacc[2];
    #pragma unroll
    for (int mt = 0; mt < 2; ++mt)
        #pragma unroll
        for (int r = 0; r < 16; ++r) vacc[mt][r] = 0.0f;
    #pragma unroll
    for (int ks = 0; ks < 4; ++ks) {
        short8 bw = *(const short8*)&w2r[l31 * 256 + g * 64 + ks * 16 + kh * 8];
        #pragma unroll
        for (int mt = 0; mt < 2; ++mt) {
            short8 ah = *(const short8*)(smem + (ks * 2 + kh) * PSTR_Q + ((2 * w + mt) * 32 + l31) * 16);
            vacc[mt] = __builtin_amdgcn_mfma_f32_32x32x16_bf16(ah, bw, vacc[mt], 0, 0, 0);
        }
    }

    // ---- scatter v_tap into 10x32 tile (s_h now dead -> union), then global atomics ----
    __syncthreads();
    float* s_log = (float*)smem;
    for (int i = t; i < 320; i += 256) s_log[i] = 0.0f;
    __syncthreads();
    if (l31 < 9) {
        int ky = l31 / 3, kx = l31 - ky * 3;
        #pragma unroll
        for (int mt = 0; mt < 2; ++mt) {
            int outr = 2 * w + mt + 2 - ky;       // tile row; R = r0 + outr - 1
            #pragma unroll
            for (int reg = 0; reg < 16; ++reg) {
                int col  = (reg & 3) + 8 * (reg >> 2) + 4 * kh;
                int outc = col + 1 - kx;
                if (outc >= 0 && outc < 32)
                    atomicAdd(&s_log[outr * 32 + outc], vacc[mt][reg]);
            }
        }
    }
    __syncthreads();
    for (int i = t; i < 320; i += 256) {
        int outr = i >> 5, outc = i & 31;
        int R = r0 + outr - 1;
        if ((unsigned)R < 32u)
            atomicAdd(&logits[n * 1024 + R * 32 + outc], s_log[i]);
    }

    // ---- fused BCE tail: last block of anchor n reduces its 1024 logits ----
    // NOTE: no __threadfence here (R7 lesson). __syncthreads' compiler-emitted
    // vmcnt(0) drain completes every thread's device-scope logits atomics; completed
    // device-scope atomics are globally visible (m20). Reader loads are AGENT-scope.
    __syncthreads();
    if (t == 0) {
        uint_t old = atomicAdd(&cnt[n], 1u);
        s_done = (old == 15u) ? 1 : 0;
    }
    __syncthreads();
    if (s_done) {
        const int tgt_cls = base_classes[labels[n]];
        const float bias2 = b2[0];
        float lsum = 0.0f;
        #pragma unroll
        for (int r = 0; r < 4; ++r) {
            int p = t + r * 256;
            int i = p >> 5, j = p & 31;
            float l = __hip_atomic_load(&logits[n * 1024 + p],
                                        __ATOMIC_RELAXED, __HIP_MEMORY_SCOPE_AGENT) + bias2;
            int sv = seg[(size_t)(4 * (y0 + i)) * IMGD + 4 * (x0 + j)];
            float tgt = (sv == tgt_cls) ? 1.0f : 0.0f;
            lsum += fmaxf(l, 0.0f) - l * tgt + log1pf(expf(-fabsf(l)));
        }
        #pragma unroll
        for (int off = 32; off > 0; off >>= 1) lsum += __shfl_down(lsum, off, 64);
        float* s_red = (float*)smem;
        if ((t & 63) == 0) s_red[t >> 6] = lsum;
        __syncthreads();
        if (t == 0) {
            float tot = s_red[0] + s_red[1] + s_red[2] + s_red[3];
            const float scale = 1.0f / (1024.0f * (256.0f + 1e-10f));
            atomicAdd(out, tot * scale);
        }
    }
}

extern "C" void kernel_launch(void* const* d_in, const int* in_sizes, int n_in,
                              void* d_out, int out_size, void* d_ws, size_t ws_size,
                              hipStream_t stream) {
    const float* fm           = (const float*)d_in[0];
    const int*   seg          = (const int*)d_in[1];
    const int*   anchors      = (const int*)d_in[2];
    const int*   labels       = (const int*)d_in[3];
    const int*   base_classes = (const int*)d_in[4];
    const float* W1           = (const float*)d_in[5];
    const float* b1           = (const float*)d_in[6];
    const float* W2           = (const float*)d_in[7];
    const float* b2           = (const float*)d_in[8];
    float* out = (float*)d_out;

    float*    logits = (float*)d_ws;
    uchar_t*  w1b    = (uchar_t*)((char*)d_ws + W1R_BYTE_OFF);
    ushort_t* w2r    = (ushort_t*)((char*)d_ws + W2R_BYTE_OFF);
    uint_t*   cnt    = (uint_t*)((char*)d_ws + CNT_BYTE_OFF);
    uchar_t*  fmT    = (uchar_t*)((char*)d_ws + FMT_BYTE_OFF);

    prep_kernel<<<4353, 256, 0, stream>>>(W1, W2, fm, logits, out, w1b, w2r, fmT, cnt);
    conv_mfma_kernel<<<4096, 256, 0, stream>>>(anchors, fmT, w1b, w2r, b1, logits,
                                               seg, labels, base_classes, b2, out, cnt);
}

// Round 11
// 216.667 us; speedup vs baseline: 2.1569x; 1.0333x over previous
//
#include <hip/hip_runtime.h>

typedef __attribute__((ext_vector_type(8))) short short8;
typedef __attribute__((ext_vector_type(8))) int int8v;
typedef __attribute__((ext_vector_type(16))) float floatx16;
typedef __attribute__((ext_vector_type(4))) unsigned int uint4v;
typedef unsigned short ushort_t;
typedef unsigned int uint_t;
typedef unsigned char uchar_t;

#define NA   256
#define CIN  128
#define HFD  320
#define FMPX (HFD*HFD)
#define IMGD 1280

// ws layout (bytes):
//   [0, 1MB)              logits f32 (NA*1024)
//   [1MB, +294912)        w1b fp8  [tap][g][nt][c][lane64][32B]  (coalesced B-frag layout), scaled x64
//   [+294912, +311296)    w2r bf16 [32 krow][256 oc]
//   [1.5MB, +1024)        cnt  u32 [256]  per-anchor completion counters
//   [2MB, 2MB+13107200)   fmT fp8  [320 y][320 x][128 c]
#define W1R_BYTE_OFF (1u<<20)
#define W2R_BYTE_OFF ((1u<<20) + 9*256*128)
#define CNT_BYTE_OFF (1536u<<10)
#define FMT_BYTE_OFF (2u<<20)

#define SAPL_M 5456   // A sub-plane stride: 340 cells*16 + 16 pad. 1364 dw == 20 mod 32
                      // -> 8 staging sub-planes land on 8 disjoint 4-bank groups
                      // (5440 would put subs {0,2,4,6}/{1,3,5,7} on 2 groups = 4-way).
#define PSTR_Q 4112   // bytes per oc-octet plane of s_h: 8*32*16 + 16 pad

union V32 { int8v v; uint4v q[2]; };

__device__ __forceinline__ ushort_t f2bf(float v) {
    uint_t u = __float_as_uint(v);
    return (ushort_t)((u + 0x8000u) >> 16);
}
__device__ __forceinline__ uchar_t f2fp8(float v) {
    int r = __builtin_amdgcn_cvt_pk_fp8_f32(v, 0.0f, 0, false);
    return (uchar_t)(r & 0xff);
}

// Fused prep: [0,3200) fm->fmT transpose/quantize (LDS-free, R10); [3200,4224) logits
// zero; [4224,4352) w1b repack; 4352: w2r + out + cnt.
__global__ __launch_bounds__(256) void prep_kernel(
    const float* __restrict__ W1, const float* __restrict__ W2,
    const float* __restrict__ fm,
    float* __restrict__ logits, float* __restrict__ out,
    uchar_t* __restrict__ w1b, ushort_t* __restrict__ w2r,
    uchar_t* __restrict__ fmT, uint_t* __restrict__ cnt)
{
    const int b = blockIdx.x, t = threadIdx.x;
    if (b < 3200) {
        const int y = b / 10, x0b = (b % 10) * 32;
        const int xo = t & 31, cg = t >> 5;
        const float* src = fm + (size_t)(cg * 16) * FMPX + (size_t)y * HFD + x0b + xo;
        float f[16];
        #pragma unroll
        for (int k = 0; k < 16; ++k) f[k] = src[(size_t)k * FMPX];
        uint4v vout;
        #pragma unroll
        for (int d = 0; d < 4; ++d) {
            int u = __builtin_amdgcn_cvt_pk_fp8_f32(f[4*d],   f[4*d+1], 0, false);
            u     = __builtin_amdgcn_cvt_pk_fp8_f32(f[4*d+2], f[4*d+3], u, true);
            vout[d] = (uint_t)u;
        }
        *(uint4v*)&fmT[((size_t)(y * HFD + x0b + xo)) * 128 + cg * 16] = vout;
    } else if (b < 4224) {
        logits[(b - 3200) * 256 + t] = 0.0f;
    } else if (b < 4352) {
        int e = (b - 4224) * 256 + t;
        int oc = e >> 7, cin = e & 127;
        int g = oc >> 6, nt = (oc >> 5) & 1, lv = oc & 31;
        int c = cin >> 6, kh = (cin >> 5) & 1, j = cin & 31;
        #pragma unroll
        for (int tap = 0; tap < 9; ++tap) {
            int idx = (((((tap * 4 + g) * 2 + nt) * 2 + c) * 64) + kh * 32 + lv) * 32 + j;
            w1b[idx] = f2fp8(W1[(oc * 128 + cin) * 9 + tap] * 64.0f);
        }
    } else {
        #pragma unroll
        for (int i = 0; i < 32; ++i) {
            int e = i * 256 + t;
            int nrow = e >> 8, oc = e & 255;
            w2r[nrow * 256 + oc] = f2bf(nrow < 9 ? W2[oc * 9 + nrow] : 0.0f);
        }
        cnt[t] = 0u;
        if (t == 0) out[0] = 0.0f;
    }
}

// Block = (anchor, 8-row quarter, 64-oc group); grid 4096, XCD-swizzled.
// R11: R6's frozen MFMA loop + MERGED A-staging (R4's one good idea, isolated): all
// 128 cin staged ONCE (8 sub-planes, 43.6 KB, stride 5456 for full 32-bank coverage
// of the 8-lane staging writes) -> ONE barrier pair total; the 18 MFMA steps run
// uninterrupted (B boundary-prefetch already crosses c0->c1 without barriers).
// Register structure IDENTICAL to R6 (bb0/1/2 static rotation, fa0-3 shared A-frags,
// unconditional loads, rolled gi) -- the R4 spill drivers (runtime step index,
// conditional buffer writes) are absent. LDS 43648 -> still 3 blocks/CU.
// SPILL HISTORY: window-widening spills (R1 450MB / R2 253MB / R4 1.7GB); R5 A-dbuf
// rotate movs -12%. Keep: static names, unconditional loads, rolled gi, (256,3).
// BCE tail: NO __threadfence (R7: all-blocks agent fence = chip-wide L2 eviction of
// the hot w1b stream, conv 122->380us; R9 fence-free: 131us, absmax 0 -- visibility
// via vmcnt-drained device-scope atomics (m20/m97) + AGENT-scope reader loads).
__global__ __launch_bounds__(256, 3) void conv_mfma_kernel(
    const int* __restrict__ anchors, const uchar_t* __restrict__ fmT,
    const uchar_t* __restrict__ w1b, const ushort_t* __restrict__ w2r,
    const float* __restrict__ b1, float* __restrict__ logits,
    const int* __restrict__ seg, const int* __restrict__ labels,
    const int* __restrict__ base_classes, const float* __restrict__ b2,
    float* __restrict__ out, uint_t* __restrict__ cnt)
{
    const int id   = blockIdx.x;
    const int xcd  = id & 7, sid = id >> 3;
    const int n    = xcd * 32 + (sid >> 4);
    const int rem  = sid & 15;
    const int q    = rem >> 2;
    const int g    = rem & 3;

    const int t    = threadIdx.x;
    const int w    = t >> 6;
    const int lane = t & 63;
    const int l31  = lane & 31;
    const int kh   = lane >> 5;

    const int x0 = anchors[n * 4 + 0];
    const int y0 = anchors[n * 4 + 2];
    const int r0 = q * 8;

    __shared__ __align__(16) char smem[8 * SAPL_M];   // 43648 B: s_a (8 planes) / s_h / s_log union
    __shared__ int s_done;
    char* s_a = smem;

    floatx16 acc[2][2];
    #pragma unroll
    for (int mt = 0; mt < 2; ++mt)
        #pragma unroll
        for (int nt = 0; nt < 2; ++nt)
            #pragma unroll
            for (int r = 0; r < 16; ++r) acc[mt][nt][r] = 0.0f;

    // B-fragment loader: tap in [0,9), cc = cin chunk
    auto loadB = [&](int tap, int cc, V32* b) {
        #pragma unroll
        for (int nt = 0; nt < 2; ++nt) {
            const uchar_t* bp = w1b + ((((tap * 4 + g) * 2 + nt) * 2 + cc) << 11) + lane * 32;
            b[nt].q[0] = *(const uint4v*)(bp);
            b[nt].q[1] = *(const uint4v*)(bp + 16);
        }
    };

#define MF4(AL, AH, BB)                                                                   \
    acc[0][0] = __builtin_amdgcn_mfma_scale_f32_32x32x64_f8f6f4(                          \
        (AL).v, (BB)[0].v, acc[0][0], 0, 0, 0, 127, 0, 127);                              \
    acc[0][1] = __builtin_amdgcn_mfma_scale_f32_32x32x64_f8f6f4(                          \
        (AL).v, (BB)[1].v, acc[0][1], 0, 0, 0, 127, 0, 127);                              \
    acc[1][0] = __builtin_amdgcn_mfma_scale_f32_32x32x64_f8f6f4(                          \
        (AH).v, (BB)[0].v, acc[1][0], 0, 0, 0, 127, 0, 127);                              \
    acc[1][1] = __builtin_amdgcn_mfma_scale_f32_32x32x64_f8f6f4(                          \
        (AH).v, (BB)[1].v, acc[1][1], 0, 0, 0, 127, 0, 127);

    V32 bb0[2], bb1[2], bb2[2];
    // prime: s=0 -> (kx=0,ky=0) tap 0; s=1 -> (kx=0,ky=1) tap 3; both chunk 0
    loadB(0, 0, bb0);
    loadB(3, 0, bb1);

    // zero col pads: 8 planes x 10 rows x 2 cols = 160 units
    if (t < 160) {
        int p = t & 7, k = t >> 3;
        int pr = k >> 1, col = (k & 1) * 33;
        uint4v z = {0u, 0u, 0u, 0u};
        *(uint4v*)(s_a + p * SAPL_M + (pr * 34 + col) * 16) = z;
    }
    // ---- stage A ONCE: 10 rows x 32 cols x 8 subs = 2560 uint4 units (10 iters) ----
    // 8 consecutive lanes cover one (y,x)'s full 128 B -> coalesced. Halo rows zero.
    #pragma unroll
    for (int j = 0; j < 10; ++j) {
        int u = t + 256 * j;
        int sub = u & 7, cell10 = u >> 3;
        int pr = cell10 >> 5, col = cell10 & 31;
        int cr = r0 + pr - 1;
        uint4v v = {0u, 0u, 0u, 0u};
        if ((unsigned)cr < 32u)
            v = *(const uint4v*)&fmT[((size_t)((y0 + cr) * HFD + x0 + col)) * 128 + sub * 16];
        *(uint4v*)(s_a + sub * SAPL_M + (pr * 34 + col + 1) * 16) = v;
    }
    __syncthreads();   // the ONLY pre-MFMA barrier

    #pragma unroll 1
    for (int c = 0; c < 2; ++c) {
        // ---- MFMA: gi = kx rolled; ky unrolled with static buffer naming ----
        #pragma unroll 1
        for (int gi = 0; gi < 3; ++gi) {
            // 4 shared A-frags: rows 2w..2w+3 at col offset gi (one addr + imm offsets)
            V32 fa0, fa1, fa2, fa3;
            {
                const char* ap = s_a + (c * 4 + 2 * kh) * SAPL_M + ((2 * w) * 34 + l31 + gi) * 16;
                fa0.q[0] = *(const uint4v*)(ap);
                fa0.q[1] = *(const uint4v*)(ap + SAPL_M);
                fa1.q[0] = *(const uint4v*)(ap + 544);
                fa1.q[1] = *(const uint4v*)(ap + SAPL_M + 544);
                fa2.q[0] = *(const uint4v*)(ap + 1088);
                fa2.q[1] = *(const uint4v*)(ap + SAPL_M + 1088);
                fa3.q[0] = *(const uint4v*)(ap + 1632);
                fa3.q[1] = *(const uint4v*)(ap + SAPL_M + 1632);
            }
            // boundary-aware prefetch taps (affine in gi; unconditional loads)
            const int last = (gi == 2);
            const int tapk1 = last ? 0 : gi + 1;      // next step (gi+1,0) / next chunk (0,0)
            const int tapk2 = last ? 3 : gi + 4;      // next step (gi+1,1) / next chunk (0,1)
            const int ccn   = last ? 1 : c;           // c==1,gi==2: dead reload of cc=1 (harmless)

            // k=0: consume bb0; prefetch bb2 for (gi, k=2), tap 6+gi
            loadB(6 + gi, c, bb2);
            MF4(fa0, fa1, bb0)
            // k=1: consume bb1; prefetch bb0 for (gi+1, k=0)
            loadB(tapk1, ccn, bb0);
            MF4(fa1, fa2, bb1)
            // k=2: consume bb2; prefetch bb1 for (gi+1, k=1)
            loadB(tapk2, ccn, bb1);
            MF4(fa2, fa3, bb2)
        }
    }
#undef MF4

    // ---- epilogue: h = acc/64 + b1, relu -> s_h (bf16, 8 planes of 8 oc) ----
    __syncthreads();
    #pragma unroll
    for (int nt = 0; nt < 2; ++nt) {
        float bias = b1[g * 64 + nt * 32 + l31];
        int plane = nt * 4 + (l31 >> 3);
        #pragma unroll
        for (int mt = 0; mt < 2; ++mt) {
            int lr = 2 * w + mt;
            #pragma unroll
            for (int reg = 0; reg < 16; ++reg) {
                int col = (reg & 3) + 8 * (reg >> 2) + 4 * kh;   // C layout: m = crop col
                float hv = fmaxf(fmaf(acc[mt][nt][reg], 0.015625f, bias), 0.0f);
                *(ushort_t*)(smem + plane * PSTR_Q + ((lr * 32 + col) * 8 + (l31 & 7)) * 2) = f2bf(hv);
            }
        }
    }
    __syncthreads();

    // ---- v_tap = h @ W2^T (bf16, K=64 oc over 4 x K16) ----
    floatx16 vacc[2];
    #pragma unroll
    for (int mt = 0; mt < 2; ++mt)
        #pragma unroll
        for (int r = 0; r < 16; ++r) vacc[mt][r] = 0.0f;
    #pragma unroll
    for (int ks = 0; ks < 4; ++ks) {
        short8 bw = *(const short8*)&w2r[l31 * 256 + g * 64 + ks * 16 + kh * 8];
        #pragma unroll
        for (int mt = 0; mt < 2; ++mt) {
            short8 ah = *(const short8*)(smem + (ks * 2 + kh) * PSTR_Q + ((2 * w + mt) * 32 + l31) * 16);
            vacc[mt] = __builtin_amdgcn_mfma_f32_32x32x16_bf16(ah, bw, vacc[mt], 0, 0, 0);
        }
    }

    // ---- scatter v_tap into 10x32 tile (s_h now dead -> union), then global atomics ----
    __syncthreads();
    float* s_log = (float*)smem;
    for (int i = t; i < 320; i += 256) s_log[i] = 0.0f;
    __syncthreads();
    if (l31 < 9) {
        int ky = l31 / 3, kx = l31 - ky * 3;
        #pragma unroll
        for (int mt = 0; mt < 2; ++mt) {
            int outr = 2 * w + mt + 2 - ky;       // tile row; R = r0 + outr - 1
            #pragma unroll
            for (int reg = 0; reg < 16; ++reg) {
                int col  = (reg & 3) + 8 * (reg >> 2) + 4 * kh;
                int outc = col + 1 - kx;
                if (outc >= 0 && outc < 32)
                    atomicAdd(&s_log[outr * 32 + outc], vacc[mt][reg]);
            }
        }
    }
    __syncthreads();
    for (int i = t; i < 320; i += 256) {
        int outr = i >> 5, outc = i & 31;
        int R = r0 + outr - 1;
        if ((unsigned)R < 32u)
            atomicAdd(&logits[n * 1024 + R * 32 + outc], s_log[i]);
    }

    // ---- fused BCE tail: last block of anchor n reduces its 1024 logits ----
    // NOTE: no __threadfence here (R7 lesson). __syncthreads' compiler-emitted
    // vmcnt(0) drain completes every thread's device-scope logits atomics; completed
    // device-scope atomics are globally visible (m20). Reader loads are AGENT-scope.
    __syncthreads();
    if (t == 0) {
        uint_t old = atomicAdd(&cnt[n], 1u);
        s_done = (old == 15u) ? 1 : 0;
    }
    __syncthreads();
    if (s_done) {
        const int tgt_cls = base_classes[labels[n]];
        const float bias2 = b2[0];
        float lsum = 0.0f;
        #pragma unroll
        for (int r = 0; r < 4; ++r) {
            int p = t + r * 256;
            int i = p >> 5, j = p & 31;
            float l = __hip_atomic_load(&logits[n * 1024 + p],
                                        __ATOMIC_RELAXED, __HIP_MEMORY_SCOPE_AGENT) + bias2;
            int sv = seg[(size_t)(4 * (y0 + i)) * IMGD + 4 * (x0 + j)];
            float tgt = (sv == tgt_cls) ? 1.0f : 0.0f;
            lsum += fmaxf(l, 0.0f) - l * tgt + log1pf(expf(-fabsf(l)));
        }
        #pragma unroll
        for (int off = 32; off > 0; off >>= 1) lsum += __shfl_down(lsum, off, 64);
        float* s_red = (float*)smem;
        if ((t & 63) == 0) s_red[t >> 6] = lsum;
        __syncthreads();
        if (t == 0) {
            float tot = s_red[0] + s_red[1] + s_red[2] + s_red[3];
            const float scale = 1.0f / (1024.0f * (256.0f + 1e-10f));
            atomicAdd(out, tot * scale);
        }
    }
}

extern "C" void kernel_launch(void* const* d_in, const int* in_sizes, int n_in,
                              void* d_out, int out_size, void* d_ws, size_t ws_size,
                              hipStream_t stream) {
    const float* fm           = (const float*)d_in[0];
    const int*   seg          = (const int*)d_in[1];
    const int*   anchors      = (const int*)d_in[2];
    const int*   labels       = (const int*)d_in[3];
    const int*   base_classes = (const int*)d_in[4];
    const float* W1           = (const float*)d_in[5];
    const float* b1           = (const float*)d_in[6];
    const float* W2           = (const float*)d_in[7];
    const float* b2           = (const float*)d_in[8];
    float* out = (float*)d_out;

    float*    logits = (float*)d_ws;
    uchar_t*  w1b    = (uchar_t*)((char*)d_ws + W1R_BYTE_OFF);
    ushort_t* w2r    = (ushort_t*)((char*)d_ws + W2R_BYTE_OFF);
    uint_t*   cnt    = (uint_t*)((char*)d_ws + CNT_BYTE_OFF);
    uchar_t*  fmT    = (uchar_t*)((char*)d_ws + FMT_BYTE_OFF);

    prep_kernel<<<4353, 256, 0, stream>>>(W1, W2, fm, logits, out, w1b, w2r, fmT, cnt);
    conv_mfma_kernel<<<4096, 256, 0, stream>>>(anchors, fmT, w1b, w2r, b1, logits,
                                               seg, labels, base_classes, b2, out, cnt);
}